// Round 8
// baseline (539.509 us; speedup 1.0000x reference)
//
#include <hip/hip_runtime.h>

#define DEVFN __device__ __forceinline__

static constexpr int cB  = 16;
static constexpr int cS  = 1024;
static constexpr int cD  = 1024;
static constexpr int cPE = 20;
static constexpr int cG  = 80;   // 4*PE

typedef float  floatx2  __attribute__((ext_vector_type(2)));
typedef float  floatx4  __attribute__((ext_vector_type(4)));
typedef float  floatx16 __attribute__((ext_vector_type(16)));
typedef short  short8   __attribute__((ext_vector_type(8)));
typedef unsigned uintx2 __attribute__((ext_vector_type(2)));
typedef __fp16 half2f  __attribute__((ext_vector_type(2)));   // matches cvt_pkrtz return type

DEVFN unsigned pack_bf(float a, float b) {
  union { float f; unsigned u; } ua, ub; ua.f = a; ub.f = b;
  return (ua.u >> 16) | (ub.u & 0xffff0000u);
}
DEVFN half2f u2h(unsigned u) { union { unsigned u; half2f h; } c; c.u = u; return c.h; }
DEVFN unsigned h2u(half2f h) { union { half2f h; unsigned u; } c; c.h = h; return c.u; }

// ---------------------------------------------------------------------------
// K1: xgT[b][g][t] = (x @ W_ih^T + b_ih + b_hh) * gate_scale(g), transposed
//     for k2's streaming loads. + fused emit of x transposed to bf16.
// Round-8: retiled 64->32 rows (grid 512, LDS 30.5KB) -> 2 blocks/CU, so one
// block's compute hides the other's staging (was 1 block/CU, zero TLP, all
// global-load latency exposed at the per-kc barriers).
// ---------------------------------------------------------------------------
static constexpr int K1_XS = 68;  // LDS row stride (floats)

__global__ __launch_bounds__(256) void k1_xg(
    const float* __restrict__ x, const float* __restrict__ W_ih,
    const float* __restrict__ b_ih, const float* __restrict__ b_hh,
    float* __restrict__ xgT, unsigned short* __restrict__ xbf_t, int use_bf)
{
  __shared__ float xs[32 * K1_XS];   //  8704 B
  __shared__ float wsm[80 * K1_XS];  // 21760 B

  const int t  = threadIdx.x;
  const int rg = t >> 4, cg = t & 15;
  const int r0 = rg * 2, c0 = cg * 5;
  const int row0 = blockIdx.x * 32;
  const int b  = row0 >> 10;
  const int s0 = row0 & 1023;

  floatx2 acc[2][5];
#pragma unroll
  for (int q = 0; q < 2; ++q)
#pragma unroll
    for (int cc = 0; cc < 5; ++cc) { acc[q][cc].x = 0.f; acc[q][cc].y = 0.f; }

  for (int kc = 0; kc < 16; ++kc) {
    const int k0 = kc * 64;
    // ---- stage x tile: 32 rows x 64 k (2 float4 / thread) ----------------
    {
      const int sr = t >> 3, sc = t & 7;
      const float4* src = (const float4*)(x + (size_t)(row0 + sr) * cD + k0 + sc * 8);
      float4 v0 = src[0], v1 = src[1];
      float4* dst = (float4*)&xs[sr * K1_XS + sc * 8];
      dst[0] = v0; dst[1] = v1;
    }
    // ---- stage W tile: 80 gates x 64 k -----------------------------------
#pragma unroll
    for (int q = 0; q < 5; ++q) {
      const int id = t + q * 256;          // 0..1279
      const int g = id >> 4, c4 = id & 15;
      float4 wv = *(const float4*)(W_ih + (size_t)g * cD + k0 + c4 * 4);
      *(float4*)&wsm[g * K1_XS + c4 * 4] = wv;
    }
    __syncthreads();

    // ---- transposed bf16 emit: xbf_t[b][k0+dl][s0 + 8*sc8 + e] -----------
    if (use_bf) {
      const int dl = t >> 2, sc8 = t & 3;
      float v[8];
#pragma unroll
      for (int e = 0; e < 8; ++e) v[e] = xs[(sc8 * 8 + e) * K1_XS + dl];
      unsigned u[4];
#pragma unroll
      for (int p = 0; p < 4; ++p) u[p] = pack_bf(v[2 * p], v[2 * p + 1]);
      unsigned short* dstp = xbf_t + ((size_t)(b * cD + k0 + dl)) * cS + s0 + sc8 * 8;
      *(uint4*)dstp = make_uint4(u[0], u[1], u[2], u[3]);
    }

    // ---- compute: 32 x (7 ds_read_b64 + 10 pk_fma) -----------------------
#pragma unroll 4
    for (int k2 = 0; k2 < 32; ++k2) {
      floatx2 xv[2], wv[5];
#pragma unroll
      for (int q = 0; q < 2; ++q)
        xv[q] = *(const floatx2*)&xs[(r0 + q) * K1_XS + 2 * k2];
#pragma unroll
      for (int cc = 0; cc < 5; ++cc)
        wv[cc] = *(const floatx2*)&wsm[(c0 + cc) * K1_XS + 2 * k2];
#pragma unroll
      for (int q = 0; q < 2; ++q)
#pragma unroll
        for (int cc = 0; cc < 5; ++cc)
          acc[q][cc] += xv[q] * wv[cc];
    }
    __syncthreads();
  }

  // ---- epilogue: scaled, biased, transposed stores (floatx2 over t) ------
#pragma unroll
  for (int cc = 0; cc < 5; ++cc) {
    const int g = c0 + cc;
    const float sc = (g >= 40 && g < 60) ? 2.88539008f : 1.44269504f;
    const float bs = b_ih[g] + b_hh[g];
    floatx2 v;
    v.x = (acc[0][cc].x + acc[0][cc].y + bs) * sc;
    v.y = (acc[1][cc].x + acc[1][cc].y + bs) * sc;
    *(floatx2*)&xgT[((size_t)(b * cG + g)) * cS + s0 + r0] = v;
  }
}

// ---------------------------------------------------------------------------
// K2: LSTM scan. Round-8: WAVE-PAIRING -- 2 blocks x 512 thr; each block's
// 8 waves (one batch each) land 2-per-SIMD, so the HW interleaves two
// independent chains and fills the ~150cy/step of single-wave stalls
// (round-3's failure put 2 chains in ONE in-order wave -> issue doubled;
// this version lets the SIMD scheduler do the interleave for free).
// Scan body is byte-identical to round-7's (fdot2 f16 dots, merged rcp,
// DPP-pack + 10 readlanes); h history goes back to global hbuf (LDS can't
// hold 8 batches), so k3a/k3b return as separate kernels.
// Worst case: each wave alone is no slower than round-7's -> neutral.
// ---------------------------------------------------------------------------
__global__ __launch_bounds__(512) void k2_lstm(
    const float* __restrict__ xgT, const float* __restrict__ W_hh,
    float* __restrict__ hbuf)
{
  const int wave = threadIdx.x >> 6;
  const int lane = threadIdx.x & 63;
  const int b    = blockIdx.x * 8 + wave;
  const int half = lane >> 5;
  const int l31  = lane & 31;
  const int j    = (l31 < cPE) ? l31 : (cPE - 1);
  const float LOG2E = 1.44269504f, TWOLOG2E = 2.88539008f;

  const int rowA = half ? (20 + j) : j;          // f_j : i_j   (both sigmoid)
  const int rowB = half ? (60 + j) : (40 + j);   // o_j : g_j   (sigmoid : tanh)
  const float sB   = half ? LOG2E : TWOLOG2E;
  const float subB = half ? 0.f : 1.f;           // tanh numerator: e-1

  half2f wA16[10], wB16[10];
#pragma unroll
  for (int p = 0; p < 10; ++p) {
    wA16[p] = __builtin_amdgcn_cvt_pkrtz(W_hh[rowA * cPE + 2 * p]     * LOG2E,
                                         W_hh[rowA * cPE + 2 * p + 1] * LOG2E);
    wB16[p] = __builtin_amdgcn_cvt_pkrtz(W_hh[rowB * cPE + 2 * p]     * sB,
                                         W_hh[rowB * cPE + 2 * p + 1] * sB);
  }

  const float* baseA = xgT + ((size_t)(b * cG + rowA)) * cS;
  const float* baseB = xgT + ((size_t)(b * cG + rowB)) * cS;

  // 4-slot rotation; trailing prefetch overruns xgT by <=64B into the hbuf
  // workspace region (allocated) - safe.
  float4 bufA[4], bufB[4];
#pragma unroll
  for (int s = 0; s < 4; ++s) {
    bufA[s] = *(const float4*)(baseA + s * 4);
    bufB[s] = *(const float4*)(baseB + s * 4);
  }

  half2f hs[10];
#pragma unroll
  for (int p = 0; p < 10; ++p) hs[p] = u2h(0u);

  float c = 0.f;
  float* hb = hbuf + (size_t)b * cS * cPE + j;

  for (int q0 = 0; q0 < 256; q0 += 4) {
#pragma unroll
    for (int s = 0; s < 4; ++s) {
      const int q = q0 + s;
      const float4 gA4 = bufA[s];
      const float4 gB4 = bufB[s];
      bufA[s] = *(const float4*)(baseA + (q + 4) * 4);
      bufB[s] = *(const float4*)(baseB + (q + 4) * 4);
#pragma unroll
      for (int e = 0; e < 4; ++e) {
        const float geA = (e == 0) ? gA4.x : (e == 1) ? gA4.y : (e == 2) ? gA4.z : gA4.w;
        const float geB = (e == 0) ? gB4.x : (e == 1) ? gB4.y : (e == 2) ? gB4.z : gB4.w;

        // ---- dots: 20 fdot2 (f16 pairs, f32 acc), 4 chains of 5 ----------
        float a0 = geA, a1 = 0.f, c0v = geB, c1v = 0.f;
#pragma unroll
        for (int p = 0; p < 5; ++p) {
          a0  = __builtin_amdgcn_fdot2(wA16[p],     hs[p],     a0,  false);
          c0v = __builtin_amdgcn_fdot2(wB16[p],     hs[p],     c0v, false);
          a1  = __builtin_amdgcn_fdot2(wA16[5 + p], hs[5 + p], a1,  false);
          c1v = __builtin_amdgcn_fdot2(wB16[5 + p], hs[5 + p], c1v, false);
        }
        const float gAv = a0 + a1;
        const float gBv = c0v + c1v;

        // ---- activations: merged rcp -------------------------------------
        const float eA = __builtin_amdgcn_exp2f(gAv);
        const float eB = __builtin_amdgcn_exp2f(gBv);
        const float pA = eA + 1.f, pB = eB + 1.f;
        const float rr = __builtin_amdgcn_rcpf(pA * pB);
        const float actA = eA * pB * rr;             // sigmoid(i|f)
        const float actB = (eB - subB) * (pA * rr);  // tanh(g) | sigmoid(o)

        // ---- half-swap gathers: .x = low bcast (i|g), .y = high (f|o) ----
        union { float f; unsigned u; } ca, cb;
        ca.f = actA; cb.f = actB;
        uintx2 rA = __builtin_amdgcn_permlane32_swap(ca.u, ca.u, false, false);
        uintx2 rB = __builtin_amdgcn_permlane32_swap(cb.u, cb.u, false, false);
        union { unsigned u; float f; } vf, vi, vg, vo;
        vi.u = rA.x; vf.u = rA.y; vg.u = rB.x; vo.u = rB.y;

        // ---- state update (identical on both halves) ---------------------
        c = vf.f * c + vi.f * vg.f;
        const float ec = __builtin_amdgcn_exp2f(fminf(TWOLOG2E * c, 30.f));
        const float th = (ec - 1.f) * __builtin_amdgcn_rcpf(ec + 1.f);
        const float hj = vo.f * th;

        if (lane < cPE) hb[(size_t)(q * 4 + e) * cPE] = hj;

        // ---- pack h pair (DPP neighbor) + 10 readlanes -------------------
        union { float f; int i; } hji; hji.f = hj;
        const int nbi = __builtin_amdgcn_mov_dpp(hji.i, 0xB1, 0xF, 0xF, true);
        union { int i; float f; } nbf; nbf.i = nbi;
        const half2f pk = __builtin_amdgcn_cvt_pkrtz(hj, nbf.f);  // even lanes: {h2p,h2p+1}
        const unsigned pku = h2u(pk);
        hs[0] = u2h((unsigned)__builtin_amdgcn_readlane((int)pku, 0));
        hs[1] = u2h((unsigned)__builtin_amdgcn_readlane((int)pku, 2));
        hs[2] = u2h((unsigned)__builtin_amdgcn_readlane((int)pku, 4));
        hs[3] = u2h((unsigned)__builtin_amdgcn_readlane((int)pku, 6));
        hs[4] = u2h((unsigned)__builtin_amdgcn_readlane((int)pku, 8));
        hs[5] = u2h((unsigned)__builtin_amdgcn_readlane((int)pku, 10));
        hs[6] = u2h((unsigned)__builtin_amdgcn_readlane((int)pku, 12));
        hs[7] = u2h((unsigned)__builtin_amdgcn_readlane((int)pku, 14));
        hs[8] = u2h((unsigned)__builtin_amdgcn_readlane((int)pku, 16));
        hs[9] = u2h((unsigned)__builtin_amdgcn_readlane((int)pku, 18));
      }
    }
  }
}

// ---------------------------------------------------------------------------
// K3a: muwT[g][r] = relu(h@W_mu^T + b_mu), sigma = sigmoid(h@W_sig^T + b_sig)
// (round-4 version, restored after un-fusing from k2)
// ---------------------------------------------------------------------------
__global__ __launch_bounds__(256) void k3a_muw(
    const float* __restrict__ hbuf,
    const float* __restrict__ W_mu, const float* __restrict__ b_mu,
    const float* __restrict__ W_sig, const float* __restrict__ b_sig,
    float* __restrict__ muwT, float* __restrict__ sigma)
{
  __shared__ float sw[84];
  const int t = threadIdx.x;
  if (t < 60) sw[t] = W_mu[t];
  else if (t < 80) sw[t] = W_sig[t - 60];
  else if (t < 83) sw[t] = b_mu[t - 80];
  else if (t == 83) sw[t] = b_sig[0];
  __syncthreads();

  const int r = blockIdx.x * 256 + t;
  const float4* hp = (const float4*)(hbuf + (size_t)r * cPE);
  float h[20];
#pragma unroll
  for (int q2 = 0; q2 < 5; ++q2) {
    float4 v = hp[q2];
    h[4 * q2] = v.x; h[4 * q2 + 1] = v.y; h[4 * q2 + 2] = v.z; h[4 * q2 + 3] = v.w;
  }
  float m0 = sw[80], m1 = sw[81], m2 = sw[82], sg = sw[83];
#pragma unroll
  for (int p = 0; p < 20; ++p) {
    m0 += sw[p]      * h[p];
    m1 += sw[20 + p] * h[p];
    m2 += sw[40 + p] * h[p];
    sg += sw[60 + p] * h[p];
  }
  muwT[r]                 = fmaxf(m0, 0.f);
  muwT[cB * cS + r]       = fmaxf(m1, 0.f);
  muwT[2 * cB * cS + r]   = fmaxf(m2, 0.f);
  sigma[r] = __builtin_amdgcn_rcpf(1.f + __builtin_amdgcn_exp2f(-1.44269504f * sg));
}

// ---------------------------------------------------------------------------
// K3b: sequential mu recurrence, 16 chains, depth-8 rolling prefetch.
// (round-4 version, restored)
// ---------------------------------------------------------------------------
__global__ __launch_bounds__(64) void k3b_mu(
    const float* __restrict__ muwT, float* __restrict__ mu)
{
  const int t = threadIdx.x;
  if (t >= cB) return;
  const float* s0p = muwT + (size_t)t * cS;
  const float* s1p = muwT + cB * cS + (size_t)t * cS;
  const float* s2p = muwT + 2 * cB * cS + (size_t)t * cS;
  float* mb = mu + (size_t)t * cS;
  const float inv = 1.f / (float)cS;

  float4 b0[8], b1[8], b2[8];
#pragma unroll
  for (int u = 0; u < 8; ++u) {
    b0[u] = *(const float4*)(s0p + u * 4);
    b1[u] = *(const float4*)(s1p + u * 4);
    b2[u] = *(const float4*)(s2p + u * 4);
  }

  float m = 0.f;
  for (int t8 = 0; t8 < 32; ++t8) {
#pragma unroll
    for (int u = 0; u < 8; ++u) {
      const int t4 = t8 * 8 + u;
      float4 w0 = b0[u], w1 = b1[u], w2 = b2[u];
      if (t4 < 248) {
        b0[u] = *(const float4*)(s0p + (t4 + 8) * 4);
        b1[u] = *(const float4*)(s1p + (t4 + 8) * 4);
        b2[u] = *(const float4*)(s2p + (t4 + 8) * 4);
      }
      const int tt = t4 * 4;
      m = w0.x * m + (w1.x + w2.x * (float)(tt + 1)) * inv; mb[tt]     = m;
      m = w0.y * m + (w1.y + w2.y * (float)(tt + 2)) * inv; mb[tt + 1] = m;
      m = w0.z * m + (w1.z + w2.z * (float)(tt + 3)) * inv; mb[tt + 2] = m;
      m = w0.w * m + (w1.w + w2.w * (float)(tt + 4)) * inv; mb[tt + 3] = m;
    }
  }
}

// ---------------------------------------------------------------------------
// K4: fused positional attention with 32x32x16 bf16 MFMA. (round-7 version
// + dh=1 waves skip the dead nrm2 accumulation: only dh=0 waves' snrm is
// ever read.)
// ---------------------------------------------------------------------------
static constexpr int TJ = 64, TD = 128, KI = 32, RS = 40;  // RS: LDS row stride (shorts)

__global__ __launch_bounds__(256) void k4_attn(
    const float* __restrict__ x, const unsigned short* __restrict__ xbf_t,
    int use_bf, const float* __restrict__ mu, const float* __restrict__ sigma,
    float* __restrict__ out)
{
  __shared__ unsigned short xsT[2][TD * RS];   // 20480 B
  __shared__ float snrm[2][32];
  __shared__ float sscl[2][32];

  const int b   = blockIdx.z;
  const int jt0 = blockIdx.x * TJ;
  const int dt0 = blockIdx.y * TD;
  const int tid = threadIdx.x;
  const int wave = tid >> 6, lane = tid & 63;
  const int jh = wave & 1, dh = wave >> 1;
  const int n32 = lane & 31, half = lane >> 5;
  const int jrow = jt0 + jh * 32 + n32;

  const float muv  = mu[b * cS + jrow];
  const float sg   = sigma[b * cS + jrow];
  const float invj = 1.f / (float)(jrow + 1);
  const float ce   = -0.72134752f / (sg * sg);   // -log2(e)/(2*sigma^2)

  float nrm2 = 0.f;
  floatx16 acc0 = (floatx16)0.f, acc1 = (floatx16)0.f;

  const int iend = jt0 + TJ;

  auto stage = [&](int pb, int i0) {
    if (use_bf) {
#pragma unroll
      for (int q = 0; q < 2; ++q) {
        const int cc = tid + q * 256;
        const int dl = cc >> 2, part = cc & 3;
        uint4 v = *(const uint4*)(xbf_t + ((size_t)(b * cD + dt0 + dl)) * cS + i0 + part * 8);
        *(uint4*)&xsT[pb][dl * RS + part * 8] = v;
      }
    } else {
#pragma unroll
      for (int q = 0; q < 2; ++q) {
        const int cc = tid + q * 256;
        const int i = cc & 31, d8 = cc >> 5;
        const float* xp = x + ((size_t)(b * cS + i0 + i)) * cD + dt0 + d8 * 8;
        float4 f0 = *(const float4*)xp;
        float4 f1 = *(const float4*)(xp + 4);
        float vv[8] = {f0.x, f0.y, f0.z, f0.w, f1.x, f1.y, f1.z, f1.w};
#pragma unroll
        for (int e = 0; e < 8; ++e) {
          union { float f; unsigned u; } cv; cv.f = vv[e];
          xsT[pb][(d8 * 8 + e) * RS + i] = (unsigned short)(cv.u >> 16);
        }
      }
    }
  };

  stage(0, 0);
  __syncthreads();

  int pb = 0;
  for (int i0 = 0; i0 < iend; i0 += KI) {
    if (i0 + KI < iend) stage(pb ^ 1, i0 + KI);

    // ---- A fragments (w values), kc = 0,1 --------------------------------
    short8 af0, af1;
#pragma unroll
    for (int kc = 0; kc < 2; ++kc) {
      short8 af;
#pragma unroll
      for (int e = 0; e < 8; ++e) {
        const int ig = i0 + kc * 16 + half * 8 + e;
        const float d = fmaf((float)ig, invj, -muv);
        float w = __builtin_amdgcn_exp2f(ce * d * d);
        w = (ig <= jrow) ? w : 0.f;
        if (dh == 0) nrm2 += w * w;   // dh=1 waves' snrm is never read
        union { float f; unsigned u; } cv; cv.f = w;
        af[e] = (short)(cv.u >> 16);
      }
      if (kc == 0) af0 = af; else af1 = af;
    }

    // ---- B fragments (one ds_read_b128 each) + MFMA ----------------------
    const int rbase = dh * 64 + n32;
    short8 b00 = *(const short8*)&xsT[pb][(rbase)      * RS + half * 8];
    short8 b01 = *(const short8*)&xsT[pb][(rbase)      * RS + 16 + half * 8];
    short8 b10 = *(const short8*)&xsT[pb][(rbase + 32) * RS + half * 8];
    short8 b11 = *(const short8*)&xsT[pb][(rbase + 32) * RS + 16 + half * 8];
    acc0 = __builtin_amdgcn_mfma_f32_32x32x16_bf16(af0, b00, acc0, 0, 0, 0);
    acc0 = __builtin_amdgcn_mfma_f32_32x32x16_bf16(af1, b01, acc0, 0, 0, 0);
    acc1 = __builtin_amdgcn_mfma_f32_32x32x16_bf16(af0, b10, acc1, 0, 0, 0);
    acc1 = __builtin_amdgcn_mfma_f32_32x32x16_bf16(af1, b11, acc1, 0, 0, 0);

    __syncthreads();
    pb ^= 1;
  }

  // ---- norms --------------------------------------------------------------
  nrm2 += __shfl_xor(nrm2, 32);
  if (wave < 2 && half == 0) snrm[jh][n32] = nrm2;
  __syncthreads();
  if (tid < 64)
    sscl[tid >> 5][tid & 31] =
        __builtin_amdgcn_rcpf(fmaxf(sqrtf(snrm[tid >> 5][tid & 31]), 1e-12f));
  __syncthreads();

  float srow[16];
#pragma unroll
  for (int reg = 0; reg < 16; ++reg) {
    const int row = (reg & 3) + 8 * (reg >> 2) + 4 * half;
    srow[reg] = sscl[jh][row];
  }
#pragma unroll
  for (int reg = 0; reg < 16; ++reg) {
    const int row = (reg & 3) + 8 * (reg >> 2) + 4 * half;
    const int jg = jt0 + jh * 32 + row;
    const int d0 = dt0 + dh * 64 + n32;
    out[((size_t)(b * cS + jg)) * cD + d0]      = acc0[reg] * srow[reg];
    out[((size_t)(b * cS + jg)) * cD + d0 + 32] = acc1[reg] * srow[reg];
  }
}

// ---------------------------------------------------------------------------
extern "C" void kernel_launch(void* const* d_in, const int* in_sizes, int n_in,
                              void* d_out, int out_size, void* d_ws, size_t ws_size,
                              hipStream_t stream) {
  const float* x     = (const float*)d_in[0];
  const float* W_ih  = (const float*)d_in[1];
  const float* W_hh  = (const float*)d_in[2];
  const float* b_ih  = (const float*)d_in[3];
  const float* b_hh  = (const float*)d_in[4];
  const float* W_mu  = (const float*)d_in[5];
  const float* b_mu  = (const float*)d_in[6];
  const float* W_sig = (const float*)d_in[7];
  const float* b_sig = (const float*)d_in[8];
  float* out = (float*)d_out;

  char* ws = (char*)d_ws;
  const size_t off_xg  = 0;                                   // 16*80*1024*4
  const size_t off_h   = off_xg  + (size_t)cB*cS*cG*4;
  const size_t off_muw = off_h   + (size_t)cB*cS*cPE*4;
  const size_t off_sig = off_muw + (size_t)cB*cS*3*4;
  const size_t off_mu  = off_sig + (size_t)cB*cS*4;
  const size_t off_xbf = off_mu  + (size_t)cB*cS*4;
  const size_t need_bf = off_xbf + (size_t)cB*cS*cD*2;

  float* xgT   = (float*)(ws + off_xg);
  float* hbuf  = (float*)(ws + off_h);
  float* muwT  = (float*)(ws + off_muw);
  float* sigma = (float*)(ws + off_sig);
  float* mu    = (float*)(ws + off_mu);
  unsigned short* xbf_t = (unsigned short*)(ws + off_xbf);
  const int use_bf = (ws_size >= need_bf) ? 1 : 0;

  k1_xg  <<<dim3(cB * cS / 32),  dim3(256), 0, stream>>>(x, W_ih, b_ih, b_hh, xgT, xbf_t, use_bf);
  k2_lstm<<<dim3(2),             dim3(512), 0, stream>>>(xgT, W_hh, hbuf);
  k3a_muw<<<dim3(cB * cS / 256), dim3(256), 0, stream>>>(hbuf, W_mu, b_mu, W_sig, b_sig, muwT, sigma);
  k3b_mu <<<dim3(1),             dim3(64),  0, stream>>>(muwT, mu);
  k4_attn<<<dim3(cS/TJ, cD/TD, cB), dim3(256), 0, stream>>>(x, xbf_t, use_bf, mu, sigma, out);
}

// Round 9
// 423.780 us; speedup vs baseline: 1.2731x; 1.2731x over previous
//
#include <hip/hip_runtime.h>

#define DEVFN __device__ __forceinline__

static constexpr int cB  = 16;
static constexpr int cS  = 1024;
static constexpr int cD  = 1024;
static constexpr int cPE = 20;
static constexpr int cG  = 80;   // 4*PE

typedef float  floatx2  __attribute__((ext_vector_type(2)));
typedef float  floatx4  __attribute__((ext_vector_type(4)));
typedef float  floatx16 __attribute__((ext_vector_type(16)));
typedef short  short8   __attribute__((ext_vector_type(8)));
typedef unsigned uintx2 __attribute__((ext_vector_type(2)));
typedef __fp16 half2f  __attribute__((ext_vector_type(2)));   // matches cvt_pkrtz return type

DEVFN unsigned pack_bf(float a, float b) {
  union { float f; unsigned u; } ua, ub; ua.f = a; ub.f = b;
  return (ua.u >> 16) | (ub.u & 0xffff0000u);
}
DEVFN half2f u2h(unsigned u) { union { unsigned u; half2f h; } c; c.u = u; return c.h; }
DEVFN unsigned h2u(half2f h) { union { half2f h; unsigned u; } c; c.h = h; return c.u; }

// ---------------------------------------------------------------------------
// K1: xgT[b][g][t] = (x @ W_ih^T + b_ih + b_hh) * gate_scale(g), transposed
//     for k2's streaming loads. gate_scale = 2*log2e for g in [40,60) (the
//     tanh gate), log2e otherwise.
//     + fused emit of x transposed to bf16: xbf_t[b][d][s] for k4.
// Tile: 64 rows x 80 gates, K-chunks of 64. Grid = 256 blocks.
// (round-7 version; round-8's 32-row retile was bundled into a regression
//  and is reverted unmeasured.)
// ---------------------------------------------------------------------------
static constexpr int K1_XS = 68;  // LDS row stride (floats)

__global__ __launch_bounds__(256) void k1_xg(
    const float* __restrict__ x, const float* __restrict__ W_ih,
    const float* __restrict__ b_ih, const float* __restrict__ b_hh,
    float* __restrict__ xgT, unsigned short* __restrict__ xbf_t, int use_bf)
{
  __shared__ float xs[64 * K1_XS];   // 17408 B
  __shared__ float wsm[80 * K1_XS];  // 21760 B

  const int t  = threadIdx.x;
  const int rg = t >> 4, cg = t & 15;
  const int r0 = rg * 4, c0 = cg * 5;
  const int row0 = blockIdx.x * 64;
  const int b  = row0 >> 10;
  const int s0 = row0 & 1023;

  floatx2 acc[4][5];
#pragma unroll
  for (int q = 0; q < 4; ++q)
#pragma unroll
    for (int cc = 0; cc < 5; ++cc) { acc[q][cc].x = 0.f; acc[q][cc].y = 0.f; }

  for (int kc = 0; kc < 16; ++kc) {
    const int k0 = kc * 64;
    // ---- stage x tile: 64 rows x 64 k ------------------------------------
    {
      const int sr = t >> 2, sc = t & 3;
      const float4* src = (const float4*)(x + (size_t)(row0 + sr) * cD + k0 + sc * 16);
      float4 v0 = src[0], v1 = src[1], v2 = src[2], v3 = src[3];
      float4* dst = (float4*)&xs[sr * K1_XS + sc * 16];
      dst[0] = v0; dst[1] = v1; dst[2] = v2; dst[3] = v3;
    }
    // ---- stage W tile: 80 gates x 64 k -----------------------------------
#pragma unroll
    for (int q = 0; q < 5; ++q) {
      const int id = t + q * 256;          // 0..1279
      const int g = id >> 4, c4 = id & 15;
      float4 wv = *(const float4*)(W_ih + (size_t)g * cD + k0 + c4 * 4);
      *(float4*)&wsm[g * K1_XS + c4 * 4] = wv;
    }
    __syncthreads();

    // ---- transposed bf16 emit: xbf_t[b][k0+dl][s0 + 16*sc4 + e] ----------
    if (use_bf) {
      const int dl = t >> 2, sc4 = t & 3;
      float v[16];
#pragma unroll
      for (int e = 0; e < 16; ++e) v[e] = xs[(sc4 * 16 + e) * K1_XS + dl];
      unsigned u[8];
#pragma unroll
      for (int p = 0; p < 8; ++p) u[p] = pack_bf(v[2 * p], v[2 * p + 1]);
      unsigned short* dstp = xbf_t + ((size_t)(b * cD + k0 + dl)) * cS + s0 + sc4 * 16;
      *(uint4*)dstp       = make_uint4(u[0], u[1], u[2], u[3]);
      *(uint4*)(dstp + 8) = make_uint4(u[4], u[5], u[6], u[7]);
    }

    // ---- compute: 32 x (9 ds_read_b64 + 20 pk_fma) -----------------------
#pragma unroll 4
    for (int k2 = 0; k2 < 32; ++k2) {
      floatx2 xv[4], wv[5];
#pragma unroll
      for (int q = 0; q < 4; ++q)
        xv[q] = *(const floatx2*)&xs[(r0 + q) * K1_XS + 2 * k2];
#pragma unroll
      for (int cc = 0; cc < 5; ++cc)
        wv[cc] = *(const floatx2*)&wsm[(c0 + cc) * K1_XS + 2 * k2];
#pragma unroll
      for (int q = 0; q < 4; ++q)
#pragma unroll
        for (int cc = 0; cc < 5; ++cc)
          acc[q][cc] += xv[q] * wv[cc];
    }
    __syncthreads();
  }

  // ---- epilogue: scaled, biased, transposed stores (float4 over t) -------
#pragma unroll
  for (int cc = 0; cc < 5; ++cc) {
    const int g = c0 + cc;
    const float sc = (g >= 40 && g < 60) ? 2.88539008f : 1.44269504f;
    const float bs = b_ih[g] + b_hh[g];
    float4 v;
    v.x = (acc[0][cc].x + acc[0][cc].y + bs) * sc;
    v.y = (acc[1][cc].x + acc[1][cc].y + bs) * sc;
    v.z = (acc[2][cc].x + acc[2][cc].y + bs) * sc;
    v.w = (acc[3][cc].x + acc[3][cc].y + bs) * sc;
    *(float4*)&xgT[((size_t)(b * cG + g)) * cS + s0 + r0] = v;
  }
}

// ---------------------------------------------------------------------------
// K2 (fused with k3a/k3b): LSTM scan + mu_w/sigma heads + mu recurrence.
// One wave per batch, grid = 16. (round-7 structure, measured 164us.)
// Round-8's wave-pairing (2 waves/SIMD) gave only 22% overlap -> chain is
// SIMD-resource-dense, not stall-padded; reverted. One local edit here:
// tanh re-formed as th = 1 - 2*rcp(ec+1), which saturates to +-1 at
// ec=inf/0, so the fminf overflow clamp is deleted from the c->h chain.
//  - gate dots in f16 v_dot2 (W_hh pre-scaled, packed half2)
//  - h broadcast: DPP neighbor + cvt_pkrtz -> 10 readlanes of half2
//  - merged sigmoid rcp: r = rcp((eA+1)(eB+1))
//  - h history in LDS (80 KB); fused muw/sigma + lane-0 mu chain tail
// Lane layout: low half A=i_j B=g_j, high half A=f_j B=o_j;
// permlane32_swap(act,act): .x = low-half bcast (i|g), .y = high (f|o).
// ---------------------------------------------------------------------------
__global__ __launch_bounds__(64) void k2_lstm(
    const float* __restrict__ xgT, const float* __restrict__ W_hh,
    const float* __restrict__ W_mu, const float* __restrict__ b_mu,
    const float* __restrict__ W_sig, const float* __restrict__ b_sig,
    float* __restrict__ sigma, float* __restrict__ mu)
{
  __shared__ float hsh[cS * cPE];   // 81920 B  h history
  __shared__ float mw0[cS];         //  4096 B  relu(mu_w0)
  __shared__ float ksc[cS];         //  4096 B  (m1 + m2*(j+1))/S
  __shared__ float mubuf[cS];       //  4096 B  mu result

  const int b    = blockIdx.x;
  const int lane = threadIdx.x;
  const int half = lane >> 5;
  const int l31  = lane & 31;
  const int j    = (l31 < cPE) ? l31 : (cPE - 1);
  const float LOG2E = 1.44269504f, TWOLOG2E = 2.88539008f;

  const int rowA = half ? (20 + j) : j;          // f_j : i_j   (both sigmoid)
  const int rowB = half ? (60 + j) : (40 + j);   // o_j : g_j   (sigmoid : tanh)
  const float sB   = half ? LOG2E : TWOLOG2E;
  const float subB = half ? 0.f : 1.f;           // tanh numerator: e-1

  half2f wA16[10], wB16[10];
#pragma unroll
  for (int p = 0; p < 10; ++p) {
    wA16[p] = __builtin_amdgcn_cvt_pkrtz(W_hh[rowA * cPE + 2 * p]     * LOG2E,
                                         W_hh[rowA * cPE + 2 * p + 1] * LOG2E);
    wB16[p] = __builtin_amdgcn_cvt_pkrtz(W_hh[rowB * cPE + 2 * p]     * sB,
                                         W_hh[rowB * cPE + 2 * p + 1] * sB);
  }

  const float* baseA = xgT + ((size_t)(b * cG + rowA)) * cS;
  const float* baseB = xgT + ((size_t)(b * cG + rowB)) * cS;

  // 4-slot rotation; trailing prefetch overruns xgT by <=~4KB into the
  // sigma/mu workspace region (allocated, values unused) - safe.
  float4 bufA[4], bufB[4];
#pragma unroll
  for (int s = 0; s < 4; ++s) {
    bufA[s] = *(const float4*)(baseA + s * 4);
    bufB[s] = *(const float4*)(baseB + s * 4);
  }

  half2f hs[10];
#pragma unroll
  for (int p = 0; p < 10; ++p) hs[p] = u2h(0u);

  float c = 0.f;

  for (int q0 = 0; q0 < 256; q0 += 4) {
#pragma unroll
    for (int s = 0; s < 4; ++s) {
      const int q = q0 + s;
      const float4 gA4 = bufA[s];
      const float4 gB4 = bufB[s];
      bufA[s] = *(const float4*)(baseA + (q + 4) * 4);
      bufB[s] = *(const float4*)(baseB + (q + 4) * 4);
#pragma unroll
      for (int e = 0; e < 4; ++e) {
        const float geA = (e == 0) ? gA4.x : (e == 1) ? gA4.y : (e == 2) ? gA4.z : gA4.w;
        const float geB = (e == 0) ? gB4.x : (e == 1) ? gB4.y : (e == 2) ? gB4.z : gB4.w;

        // ---- dots: 20 fdot2 (f16 pairs, f32 acc), 4 chains of 5 ----------
        float a0 = geA, a1 = 0.f, c0v = geB, c1v = 0.f;
#pragma unroll
        for (int p = 0; p < 5; ++p) {
          a0  = __builtin_amdgcn_fdot2(wA16[p],     hs[p],     a0,  false);
          c0v = __builtin_amdgcn_fdot2(wB16[p],     hs[p],     c0v, false);
          a1  = __builtin_amdgcn_fdot2(wA16[5 + p], hs[5 + p], a1,  false);
          c1v = __builtin_amdgcn_fdot2(wB16[5 + p], hs[5 + p], c1v, false);
        }
        const float gAv = a0 + a1;
        const float gBv = c0v + c1v;

        // ---- activations: merged rcp (1 trans saved) ---------------------
        const float eA = __builtin_amdgcn_exp2f(gAv);
        const float eB = __builtin_amdgcn_exp2f(gBv);
        const float pA = eA + 1.f, pB = eB + 1.f;
        const float rr = __builtin_amdgcn_rcpf(pA * pB);
        const float actA = eA * pB * rr;             // sigmoid(i|f)
        const float actB = (eB - subB) * (pA * rr);  // tanh(g) | sigmoid(o)

        // ---- half-swap gathers: .x = low bcast (i|g), .y = high (f|o) ----
        union { float f; unsigned u; } ca, cb;
        ca.f = actA; cb.f = actB;
        uintx2 rA = __builtin_amdgcn_permlane32_swap(ca.u, ca.u, false, false);
        uintx2 rB = __builtin_amdgcn_permlane32_swap(cb.u, cb.u, false, false);
        union { unsigned u; float f; } vf, vi, vg, vo;
        vi.u = rA.x; vf.u = rA.y; vg.u = rB.x; vo.u = rB.y;

        // ---- state update; tanh(c) = 1 - 2/(ec+1) saturates, no clamp ----
        c = vf.f * c + vi.f * vg.f;
        const float ec = __builtin_amdgcn_exp2f(TWOLOG2E * c);
        const float th = 1.f - 2.f * __builtin_amdgcn_rcpf(ec + 1.f);
        const float hj = vo.f * th;

        if (lane < cPE) hsh[(q * 4 + e) * cPE + j] = hj;

        // ---- pack h pair (DPP neighbor) + 10 readlanes -------------------
        union { float f; int i; } hji; hji.f = hj;
        const int nbi = __builtin_amdgcn_mov_dpp(hji.i, 0xB1, 0xF, 0xF, true);
        union { int i; float f; } nbf; nbf.i = nbi;
        const half2f pk = __builtin_amdgcn_cvt_pkrtz(hj, nbf.f);  // even lanes: {h2p,h2p+1}
        const unsigned pku = h2u(pk);
        hs[0] = u2h((unsigned)__builtin_amdgcn_readlane((int)pku, 0));
        hs[1] = u2h((unsigned)__builtin_amdgcn_readlane((int)pku, 2));
        hs[2] = u2h((unsigned)__builtin_amdgcn_readlane((int)pku, 4));
        hs[3] = u2h((unsigned)__builtin_amdgcn_readlane((int)pku, 6));
        hs[4] = u2h((unsigned)__builtin_amdgcn_readlane((int)pku, 8));
        hs[5] = u2h((unsigned)__builtin_amdgcn_readlane((int)pku, 10));
        hs[6] = u2h((unsigned)__builtin_amdgcn_readlane((int)pku, 12));
        hs[7] = u2h((unsigned)__builtin_amdgcn_readlane((int)pku, 14));
        hs[8] = u2h((unsigned)__builtin_amdgcn_readlane((int)pku, 16));
        hs[9] = u2h((unsigned)__builtin_amdgcn_readlane((int)pku, 18));
      }
    }
  }

  // ======================= fused k3a: mu_w & sigma ==========================
  __syncthreads();
  const float INV_S = 1.f / (float)cS;
#pragma unroll 2
  for (int r = 0; r < 16; ++r) {
    const int row = r * 64 + lane;
    const float4* hq = (const float4*)&hsh[row * cPE];
    float h[20];
#pragma unroll
    for (int q2 = 0; q2 < 5; ++q2) {
      float4 v = hq[q2];
      h[4 * q2] = v.x; h[4 * q2 + 1] = v.y; h[4 * q2 + 2] = v.z; h[4 * q2 + 3] = v.w;
    }
    float m0 = b_mu[0], m1 = b_mu[1], m2 = b_mu[2], sg2 = b_sig[0];
#pragma unroll
    for (int p = 0; p < 20; ++p) {
      m0  += W_mu[p]      * h[p];
      m1  += W_mu[20 + p] * h[p];
      m2  += W_mu[40 + p] * h[p];
      sg2 += W_sig[p]     * h[p];
    }
    m0 = fmaxf(m0, 0.f); m1 = fmaxf(m1, 0.f); m2 = fmaxf(m2, 0.f);
    mw0[row] = m0;
    ksc[row] = (m1 + m2 * (float)(row + 1)) * INV_S;
    sigma[b * cS + row] =
        __builtin_amdgcn_rcpf(1.f + __builtin_amdgcn_exp2f(-1.44269504f * sg2));
  }
  __syncthreads();

  // ======================= fused k3b: mu recurrence =========================
  if (lane == 0) {
    float m = 0.f;
#pragma unroll 8
    for (int t2 = 0; t2 < cS; ++t2) {
      m = fmaf(mw0[t2], m, ksc[t2]);
      mubuf[t2] = m;
    }
  }
  __syncthreads();
#pragma unroll
  for (int r = 0; r < 16; ++r)
    mu[b * cS + r * 64 + lane] = mubuf[r * 64 + lane];
}

// ---------------------------------------------------------------------------
// K4: fused positional attention with 32x32x16 bf16 MFMA. (round-7 version
// + dh=1 waves skip the dead nrm2 accumulation: only dh=0 waves' snrm is
// ever read.)
// ---------------------------------------------------------------------------
static constexpr int TJ = 64, TD = 128, KI = 32, RS = 40;  // RS: LDS row stride (shorts)

__global__ __launch_bounds__(256) void k4_attn(
    const float* __restrict__ x, const unsigned short* __restrict__ xbf_t,
    int use_bf, const float* __restrict__ mu, const float* __restrict__ sigma,
    float* __restrict__ out)
{
  __shared__ unsigned short xsT[2][TD * RS];   // 20480 B
  __shared__ float snrm[2][32];
  __shared__ float sscl[2][32];

  const int b   = blockIdx.z;
  const int jt0 = blockIdx.x * TJ;
  const int dt0 = blockIdx.y * TD;
  const int tid = threadIdx.x;
  const int wave = tid >> 6, lane = tid & 63;
  const int jh = wave & 1, dh = wave >> 1;
  const int n32 = lane & 31, half = lane >> 5;
  const int jrow = jt0 + jh * 32 + n32;

  const float muv  = mu[b * cS + jrow];
  const float sg   = sigma[b * cS + jrow];
  const float invj = 1.f / (float)(jrow + 1);
  const float ce   = -0.72134752f / (sg * sg);   // -log2(e)/(2*sigma^2)

  float nrm2 = 0.f;
  floatx16 acc0 = (floatx16)0.f, acc1 = (floatx16)0.f;

  const int iend = jt0 + TJ;

  auto stage = [&](int pb, int i0) {
    if (use_bf) {
#pragma unroll
      for (int q = 0; q < 2; ++q) {
        const int cc = tid + q * 256;
        const int dl = cc >> 2, part = cc & 3;
        uint4 v = *(const uint4*)(xbf_t + ((size_t)(b * cD + dt0 + dl)) * cS + i0 + part * 8);
        *(uint4*)&xsT[pb][dl * RS + part * 8] = v;
      }
    } else {
#pragma unroll
      for (int q = 0; q < 2; ++q) {
        const int cc = tid + q * 256;
        const int i = cc & 31, d8 = cc >> 5;
        const float* xp = x + ((size_t)(b * cS + i0 + i)) * cD + dt0 + d8 * 8;
        float4 f0 = *(const float4*)xp;
        float4 f1 = *(const float4*)(xp + 4);
        float vv[8] = {f0.x, f0.y, f0.z, f0.w, f1.x, f1.y, f1.z, f1.w};
#pragma unroll
        for (int e = 0; e < 8; ++e) {
          union { float f; unsigned u; } cv; cv.f = vv[e];
          xsT[pb][(d8 * 8 + e) * RS + i] = (unsigned short)(cv.u >> 16);
        }
      }
    }
  };

  stage(0, 0);
  __syncthreads();

  int pb = 0;
  for (int i0 = 0; i0 < iend; i0 += KI) {
    if (i0 + KI < iend) stage(pb ^ 1, i0 + KI);

    // ---- A fragments (w values), kc = 0,1 --------------------------------
    short8 af0, af1;
#pragma unroll
    for (int kc = 0; kc < 2; ++kc) {
      short8 af;
#pragma unroll
      for (int e = 0; e < 8; ++e) {
        const int ig = i0 + kc * 16 + half * 8 + e;
        const float d = fmaf((float)ig, invj, -muv);
        float w = __builtin_amdgcn_exp2f(ce * d * d);
        w = (ig <= jrow) ? w : 0.f;
        if (dh == 0) nrm2 += w * w;   // dh=1 waves' snrm is never read
        union { float f; unsigned u; } cv; cv.f = w;
        af[e] = (short)(cv.u >> 16);
      }
      if (kc == 0) af0 = af; else af1 = af;
    }

    // ---- B fragments (one ds_read_b128 each) + MFMA ----------------------
    const int rbase = dh * 64 + n32;
    short8 b00 = *(const short8*)&xsT[pb][(rbase)      * RS + half * 8];
    short8 b01 = *(const short8*)&xsT[pb][(rbase)      * RS + 16 + half * 8];
    short8 b10 = *(const short8*)&xsT[pb][(rbase + 32) * RS + half * 8];
    short8 b11 = *(const short8*)&xsT[pb][(rbase + 32) * RS + 16 + half * 8];
    acc0 = __builtin_amdgcn_mfma_f32_32x32x16_bf16(af0, b00, acc0, 0, 0, 0);
    acc0 = __builtin_amdgcn_mfma_f32_32x32x16_bf16(af1, b01, acc0, 0, 0, 0);
    acc1 = __builtin_amdgcn_mfma_f32_32x32x16_bf16(af0, b10, acc1, 0, 0, 0);
    acc1 = __builtin_amdgcn_mfma_f32_32x32x16_bf16(af1, b11, acc1, 0, 0, 0);

    __syncthreads();
    pb ^= 1;
  }

  // ---- norms --------------------------------------------------------------
  nrm2 += __shfl_xor(nrm2, 32);
  if (wave < 2 && half == 0) snrm[jh][n32] = nrm2;
  __syncthreads();
  if (tid < 64)
    sscl[tid >> 5][tid & 31] =
        __builtin_amdgcn_rcpf(fmaxf(sqrtf(snrm[tid >> 5][tid & 31]), 1e-12f));
  __syncthreads();

  float srow[16];
#pragma unroll
  for (int reg = 0; reg < 16; ++reg) {
    const int row = (reg & 3) + 8 * (reg >> 2) + 4 * half;
    srow[reg] = sscl[jh][row];
  }
#pragma unroll
  for (int reg = 0; reg < 16; ++reg) {
    const int row = (reg & 3) + 8 * (reg >> 2) + 4 * half;
    const int jg = jt0 + jh * 32 + row;
    const int d0 = dt0 + dh * 64 + n32;
    out[((size_t)(b * cS + jg)) * cD + d0]      = acc0[reg] * srow[reg];
    out[((size_t)(b * cS + jg)) * cD + d0 + 32] = acc1[reg] * srow[reg];
  }
}

// ---------------------------------------------------------------------------
extern "C" void kernel_launch(void* const* d_in, const int* in_sizes, int n_in,
                              void* d_out, int out_size, void* d_ws, size_t ws_size,
                              hipStream_t stream) {
  const float* x     = (const float*)d_in[0];
  const float* W_ih  = (const float*)d_in[1];
  const float* W_hh  = (const float*)d_in[2];
  const float* b_ih  = (const float*)d_in[3];
  const float* b_hh  = (const float*)d_in[4];
  const float* W_mu  = (const float*)d_in[5];
  const float* b_mu  = (const float*)d_in[6];
  const float* W_sig = (const float*)d_in[7];
  const float* b_sig = (const float*)d_in[8];
  float* out = (float*)d_out;

  char* ws = (char*)d_ws;
  const size_t off_xg  = 0;                                   // 16*80*1024*4
  const size_t off_sig = off_xg  + (size_t)cB*cS*cG*4;
  const size_t off_mu  = off_sig + (size_t)cB*cS*4;
  const size_t off_xbf = off_mu  + (size_t)cB*cS*4;
  const size_t need_bf = off_xbf + (size_t)cB*cS*cD*2;

  float* xgT   = (float*)(ws + off_xg);
  float* sigma = (float*)(ws + off_sig);
  float* mu    = (float*)(ws + off_mu);
  unsigned short* xbf_t = (unsigned short*)(ws + off_xbf);
  const int use_bf = (ws_size >= need_bf) ? 1 : 0;

  k1_xg  <<<dim3(cB * cS / 64), dim3(256), 0, stream>>>(x, W_ih, b_ih, b_hh, xgT, xbf_t, use_bf);
  k2_lstm<<<dim3(cB),           dim3(64),  0, stream>>>(xgT, W_hh, W_mu, b_mu, W_sig, b_sig, sigma, mu);
  k4_attn<<<dim3(cS/TJ, cD/TD, cB), dim3(256), 0, stream>>>(x, xbf_t, use_bf, mu, sigma, out);
}

// Round 10
// 404.238 us; speedup vs baseline: 1.3346x; 1.0483x over previous
//
#include <hip/hip_runtime.h>

#define DEVFN __device__ __forceinline__

static constexpr int cB  = 16;
static constexpr int cS  = 1024;
static constexpr int cD  = 1024;
static constexpr int cPE = 20;
static constexpr int cG  = 80;   // 4*PE

typedef float  floatx2  __attribute__((ext_vector_type(2)));
typedef float  floatx4  __attribute__((ext_vector_type(4)));
typedef float  floatx16 __attribute__((ext_vector_type(16)));
typedef short  short8   __attribute__((ext_vector_type(8)));
typedef unsigned uintx2 __attribute__((ext_vector_type(2)));
typedef __fp16 half2f  __attribute__((ext_vector_type(2)));   // matches cvt_pkrtz return type

DEVFN unsigned pack_bf(float a, float b) {
  union { float f; unsigned u; } ua, ub; ua.f = a; ub.f = b;
  return (ua.u >> 16) | (ub.u & 0xffff0000u);
}
DEVFN half2f u2h(unsigned u) { union { unsigned u; half2f h; } c; c.u = u; return c.h; }
DEVFN unsigned h2u(half2f h) { union { half2f h; unsigned u; } c; c.h = h; return c.u; }

// ---------------------------------------------------------------------------
// K1: xgT[b][g][t] = (x @ W_ih^T + b_ih + b_hh) * gate_scale(g), transposed
//     for k2's streaming loads. + fused emit of x transposed to bf16.
// Tile: 64 rows x 80 gates, K-chunks of 64. Grid = 256 blocks. (r7 version)
// ---------------------------------------------------------------------------
static constexpr int K1_XS = 68;  // LDS row stride (floats)

__global__ __launch_bounds__(256) void k1_xg(
    const float* __restrict__ x, const float* __restrict__ W_ih,
    const float* __restrict__ b_ih, const float* __restrict__ b_hh,
    float* __restrict__ xgT, unsigned short* __restrict__ xbf_t, int use_bf)
{
  __shared__ float xs[64 * K1_XS];   // 17408 B
  __shared__ float wsm[80 * K1_XS];  // 21760 B

  const int t  = threadIdx.x;
  const int rg = t >> 4, cg = t & 15;
  const int r0 = rg * 4, c0 = cg * 5;
  const int row0 = blockIdx.x * 64;
  const int b  = row0 >> 10;
  const int s0 = row0 & 1023;

  floatx2 acc[4][5];
#pragma unroll
  for (int q = 0; q < 4; ++q)
#pragma unroll
    for (int cc = 0; cc < 5; ++cc) { acc[q][cc].x = 0.f; acc[q][cc].y = 0.f; }

  for (int kc = 0; kc < 16; ++kc) {
    const int k0 = kc * 64;
    // ---- stage x tile: 64 rows x 64 k ------------------------------------
    {
      const int sr = t >> 2, sc = t & 3;
      const float4* src = (const float4*)(x + (size_t)(row0 + sr) * cD + k0 + sc * 16);
      float4 v0 = src[0], v1 = src[1], v2 = src[2], v3 = src[3];
      float4* dst = (float4*)&xs[sr * K1_XS + sc * 16];
      dst[0] = v0; dst[1] = v1; dst[2] = v2; dst[3] = v3;
    }
    // ---- stage W tile: 80 gates x 64 k -----------------------------------
#pragma unroll
    for (int q = 0; q < 5; ++q) {
      const int id = t + q * 256;          // 0..1279
      const int g = id >> 4, c4 = id & 15;
      float4 wv = *(const float4*)(W_ih + (size_t)g * cD + k0 + c4 * 4);
      *(float4*)&wsm[g * K1_XS + c4 * 4] = wv;
    }
    __syncthreads();

    // ---- transposed bf16 emit: xbf_t[b][k0+dl][s0 + 16*sc4 + e] ----------
    if (use_bf) {
      const int dl = t >> 2, sc4 = t & 3;
      float v[16];
#pragma unroll
      for (int e = 0; e < 16; ++e) v[e] = xs[(sc4 * 16 + e) * K1_XS + dl];
      unsigned u[8];
#pragma unroll
      for (int p = 0; p < 8; ++p) u[p] = pack_bf(v[2 * p], v[2 * p + 1]);
      unsigned short* dstp = xbf_t + ((size_t)(b * cD + k0 + dl)) * cS + s0 + sc4 * 16;
      *(uint4*)dstp       = make_uint4(u[0], u[1], u[2], u[3]);
      *(uint4*)(dstp + 8) = make_uint4(u[4], u[5], u[6], u[7]);
    }

    // ---- compute: 32 x (9 ds_read_b64 + 20 pk_fma) -----------------------
#pragma unroll 4
    for (int k2 = 0; k2 < 32; ++k2) {
      floatx2 xv[4], wv[5];
#pragma unroll
      for (int q = 0; q < 4; ++q)
        xv[q] = *(const floatx2*)&xs[(r0 + q) * K1_XS + 2 * k2];
#pragma unroll
      for (int cc = 0; cc < 5; ++cc)
        wv[cc] = *(const floatx2*)&wsm[(c0 + cc) * K1_XS + 2 * k2];
#pragma unroll
      for (int q = 0; q < 4; ++q)
#pragma unroll
        for (int cc = 0; cc < 5; ++cc)
          acc[q][cc] += xv[q] * wv[cc];
    }
    __syncthreads();
  }

  // ---- epilogue: scaled, biased, transposed stores (float4 over t) -------
#pragma unroll
  for (int cc = 0; cc < 5; ++cc) {
    const int g = c0 + cc;
    const float sc = (g >= 40 && g < 60) ? 2.88539008f : 1.44269504f;
    const float bs = b_ih[g] + b_hh[g];
    float4 v;
    v.x = (acc[0][cc].x + acc[0][cc].y + bs) * sc;
    v.y = (acc[1][cc].x + acc[1][cc].y + bs) * sc;
    v.z = (acc[2][cc].x + acc[2][cc].y + bs) * sc;
    v.w = (acc[3][cc].x + acc[3][cc].y + bs) * sc;
    *(float4*)&xgT[((size_t)(b * cG + g)) * cS + s0 + r0] = v;
  }
}

// ---------------------------------------------------------------------------
// K2 (fused with k3a/k3b): LSTM scan + mu_w/sigma heads + mu recurrence.
// One wave per batch, grid = 16. EXACT round-7 scan body (164us measured):
// round-9's tanh re-form (1-2*rcp) regressed to 176us -> reverted; the
// fdot2 loop's scheduling is fragile, do not touch without asm evidence.
//  - gate dots in f16 v_dot2 (W_hh pre-scaled, packed half2)
//  - h broadcast: DPP neighbor + cvt_pkrtz -> 10 readlanes of half2
//  - merged sigmoid rcp: r = rcp((eA+1)(eB+1))
//  - h history in LDS (80 KB); fused muw/sigma + lane-0 mu chain tail
// Lane layout: low half A=i_j B=g_j, high half A=f_j B=o_j;
// permlane32_swap(act,act): .x = low-half bcast (i|g), .y = high (f|o).
// ---------------------------------------------------------------------------
__global__ __launch_bounds__(64) void k2_lstm(
    const float* __restrict__ xgT, const float* __restrict__ W_hh,
    const float* __restrict__ W_mu, const float* __restrict__ b_mu,
    const float* __restrict__ W_sig, const float* __restrict__ b_sig,
    float* __restrict__ sigma, float* __restrict__ mu)
{
  __shared__ float hsh[cS * cPE];   // 81920 B  h history
  __shared__ float mw0[cS];         //  4096 B  relu(mu_w0)
  __shared__ float ksc[cS];         //  4096 B  (m1 + m2*(j+1))/S
  __shared__ float mubuf[cS];       //  4096 B  mu result

  const int b    = blockIdx.x;
  const int lane = threadIdx.x;
  const int half = lane >> 5;
  const int l31  = lane & 31;
  const int j    = (l31 < cPE) ? l31 : (cPE - 1);
  const float LOG2E = 1.44269504f, TWOLOG2E = 2.88539008f;

  const int rowA = half ? (20 + j) : j;          // f_j : i_j   (both sigmoid)
  const int rowB = half ? (60 + j) : (40 + j);   // o_j : g_j   (sigmoid : tanh)
  const float sB   = half ? LOG2E : TWOLOG2E;
  const float subB = half ? 0.f : 1.f;           // tanh numerator: e-1

  half2f wA16[10], wB16[10];
#pragma unroll
  for (int p = 0; p < 10; ++p) {
    wA16[p] = __builtin_amdgcn_cvt_pkrtz(W_hh[rowA * cPE + 2 * p]     * LOG2E,
                                         W_hh[rowA * cPE + 2 * p + 1] * LOG2E);
    wB16[p] = __builtin_amdgcn_cvt_pkrtz(W_hh[rowB * cPE + 2 * p]     * sB,
                                         W_hh[rowB * cPE + 2 * p + 1] * sB);
  }

  const float* baseA = xgT + ((size_t)(b * cG + rowA)) * cS;
  const float* baseB = xgT + ((size_t)(b * cG + rowB)) * cS;

  // 4-slot rotation; trailing prefetch overruns xgT by <=~4KB into the
  // sigma/mu workspace region (allocated, values unused) - safe.
  float4 bufA[4], bufB[4];
#pragma unroll
  for (int s = 0; s < 4; ++s) {
    bufA[s] = *(const float4*)(baseA + s * 4);
    bufB[s] = *(const float4*)(baseB + s * 4);
  }

  half2f hs[10];
#pragma unroll
  for (int p = 0; p < 10; ++p) hs[p] = u2h(0u);

  float c = 0.f;

  for (int q0 = 0; q0 < 256; q0 += 4) {
#pragma unroll
    for (int s = 0; s < 4; ++s) {
      const int q = q0 + s;
      const float4 gA4 = bufA[s];
      const float4 gB4 = bufB[s];
      bufA[s] = *(const float4*)(baseA + (q + 4) * 4);
      bufB[s] = *(const float4*)(baseB + (q + 4) * 4);
#pragma unroll
      for (int e = 0; e < 4; ++e) {
        const float geA = (e == 0) ? gA4.x : (e == 1) ? gA4.y : (e == 2) ? gA4.z : gA4.w;
        const float geB = (e == 0) ? gB4.x : (e == 1) ? gB4.y : (e == 2) ? gB4.z : gB4.w;

        // ---- dots: 20 fdot2 (f16 pairs, f32 acc), 4 chains of 5 ----------
        float a0 = geA, a1 = 0.f, c0v = geB, c1v = 0.f;
#pragma unroll
        for (int p = 0; p < 5; ++p) {
          a0  = __builtin_amdgcn_fdot2(wA16[p],     hs[p],     a0,  false);
          c0v = __builtin_amdgcn_fdot2(wB16[p],     hs[p],     c0v, false);
          a1  = __builtin_amdgcn_fdot2(wA16[5 + p], hs[5 + p], a1,  false);
          c1v = __builtin_amdgcn_fdot2(wB16[5 + p], hs[5 + p], c1v, false);
        }
        const float gAv = a0 + a1;
        const float gBv = c0v + c1v;

        // ---- activations: merged rcp (1 trans saved) ---------------------
        const float eA = __builtin_amdgcn_exp2f(gAv);
        const float eB = __builtin_amdgcn_exp2f(gBv);
        const float pA = eA + 1.f, pB = eB + 1.f;
        const float rr = __builtin_amdgcn_rcpf(pA * pB);
        const float actA = eA * pB * rr;             // sigmoid(i|f)
        const float actB = (eB - subB) * (pA * rr);  // tanh(g) | sigmoid(o)

        // ---- half-swap gathers: .x = low bcast (i|g), .y = high (f|o) ----
        union { float f; unsigned u; } ca, cb;
        ca.f = actA; cb.f = actB;
        uintx2 rA = __builtin_amdgcn_permlane32_swap(ca.u, ca.u, false, false);
        uintx2 rB = __builtin_amdgcn_permlane32_swap(cb.u, cb.u, false, false);
        union { unsigned u; float f; } vf, vi, vg, vo;
        vi.u = rA.x; vf.u = rA.y; vg.u = rB.x; vo.u = rB.y;

        // ---- state update (round-7 exact form) ---------------------------
        c = vf.f * c + vi.f * vg.f;
        const float ec = __builtin_amdgcn_exp2f(fminf(TWOLOG2E * c, 30.f));
        const float th = (ec - 1.f) * __builtin_amdgcn_rcpf(ec + 1.f);
        const float hj = vo.f * th;

        if (lane < cPE) hsh[(q * 4 + e) * cPE + j] = hj;

        // ---- pack h pair (DPP neighbor) + 10 readlanes -------------------
        union { float f; int i; } hji; hji.f = hj;
        const int nbi = __builtin_amdgcn_mov_dpp(hji.i, 0xB1, 0xF, 0xF, true);
        union { int i; float f; } nbf; nbf.i = nbi;
        const half2f pk = __builtin_amdgcn_cvt_pkrtz(hj, nbf.f);  // even lanes: {h2p,h2p+1}
        const unsigned pku = h2u(pk);
        hs[0] = u2h((unsigned)__builtin_amdgcn_readlane((int)pku, 0));
        hs[1] = u2h((unsigned)__builtin_amdgcn_readlane((int)pku, 2));
        hs[2] = u2h((unsigned)__builtin_amdgcn_readlane((int)pku, 4));
        hs[3] = u2h((unsigned)__builtin_amdgcn_readlane((int)pku, 6));
        hs[4] = u2h((unsigned)__builtin_amdgcn_readlane((int)pku, 8));
        hs[5] = u2h((unsigned)__builtin_amdgcn_readlane((int)pku, 10));
        hs[6] = u2h((unsigned)__builtin_amdgcn_readlane((int)pku, 12));
        hs[7] = u2h((unsigned)__builtin_amdgcn_readlane((int)pku, 14));
        hs[8] = u2h((unsigned)__builtin_amdgcn_readlane((int)pku, 16));
        hs[9] = u2h((unsigned)__builtin_amdgcn_readlane((int)pku, 18));
      }
    }
  }

  // ======================= fused k3a: mu_w & sigma ==========================
  __syncthreads();
  const float INV_S = 1.f / (float)cS;
#pragma unroll 2
  for (int r = 0; r < 16; ++r) {
    const int row = r * 64 + lane;
    const float4* hq = (const float4*)&hsh[row * cPE];
    float h[20];
#pragma unroll
    for (int q2 = 0; q2 < 5; ++q2) {
      float4 v = hq[q2];
      h[4 * q2] = v.x; h[4 * q2 + 1] = v.y; h[4 * q2 + 2] = v.z; h[4 * q2 + 3] = v.w;
    }
    float m0 = b_mu[0], m1 = b_mu[1], m2 = b_mu[2], sg2 = b_sig[0];
#pragma unroll
    for (int p = 0; p < 20; ++p) {
      m0  += W_mu[p]      * h[p];
      m1  += W_mu[20 + p] * h[p];
      m2  += W_mu[40 + p] * h[p];
      sg2 += W_sig[p]     * h[p];
    }
    m0 = fmaxf(m0, 0.f); m1 = fmaxf(m1, 0.f); m2 = fmaxf(m2, 0.f);
    mw0[row] = m0;
    ksc[row] = (m1 + m2 * (float)(row + 1)) * INV_S;
    sigma[b * cS + row] =
        __builtin_amdgcn_rcpf(1.f + __builtin_amdgcn_exp2f(-1.44269504f * sg2));
  }
  __syncthreads();

  // ======================= fused k3b: mu recurrence =========================
  if (lane == 0) {
    float m = 0.f;
#pragma unroll 8
    for (int t2 = 0; t2 < cS; ++t2) {
      m = fmaf(mw0[t2], m, ksc[t2]);
      mubuf[t2] = m;
    }
  }
  __syncthreads();
#pragma unroll
  for (int r = 0; r < 16; ++r)
    mu[b * cS + r * 64 + lane] = mubuf[r * 64 + lane];
}

// ---------------------------------------------------------------------------
// K4: fused positional attention with 32x32x16 bf16 MFMA.
// Round-10: TD 128->256. w(j,i) generation (the dominant VALU cost, ~160
// inst/chunk/lane) was recomputed identically in every d-tile block; halving
// the d-tile count halves total w-gen work and xbf_t re-reads. Each wave now
// owns 32j x 128d via 4 acc fragments (8 ds_read_b128 + 8 MFMA per chunk).
// LDS 41KB (3 blocks/CU), VGPR ~120. dh=1 waves skip dead nrm2.
// ---------------------------------------------------------------------------
static constexpr int TJ = 64, TD = 256, KI = 32, RS = 40;  // RS: LDS row stride (shorts)

__global__ __launch_bounds__(256) void k4_attn(
    const float* __restrict__ x, const unsigned short* __restrict__ xbf_t,
    int use_bf, const float* __restrict__ mu, const float* __restrict__ sigma,
    float* __restrict__ out)
{
  __shared__ unsigned short xsT[2][TD * RS];   // 40960 B
  __shared__ float snrm[2][32];
  __shared__ float sscl[2][32];

  const int b   = blockIdx.z;
  const int jt0 = blockIdx.x * TJ;
  const int dt0 = blockIdx.y * TD;
  const int tid = threadIdx.x;
  const int wave = tid >> 6, lane = tid & 63;
  const int jh = wave & 1, dh = wave >> 1;
  const int n32 = lane & 31, half = lane >> 5;
  const int jrow = jt0 + jh * 32 + n32;

  const float muv  = mu[b * cS + jrow];
  const float sg   = sigma[b * cS + jrow];
  const float invj = 1.f / (float)(jrow + 1);
  const float ce   = -0.72134752f / (sg * sg);   // -log2(e)/(2*sigma^2)

  float nrm2 = 0.f;
  floatx16 acc0 = (floatx16)0.f, acc1 = (floatx16)0.f;
  floatx16 acc2 = (floatx16)0.f, acc3 = (floatx16)0.f;

  const int iend = jt0 + TJ;

  auto stage = [&](int pb, int i0) {
    if (use_bf) {
#pragma unroll
      for (int q = 0; q < 4; ++q) {
        const int cc = tid + q * 256;
        const int dl = cc >> 2, part = cc & 3;   // dl: 0..255
        uint4 v = *(const uint4*)(xbf_t + ((size_t)(b * cD + dt0 + dl)) * cS + i0 + part * 8);
        *(uint4*)&xsT[pb][dl * RS + part * 8] = v;
      }
    } else {
#pragma unroll
      for (int q = 0; q < 4; ++q) {
        const int cc = tid + q * 256;
        const int i = cc & 31, d8 = cc >> 5;     // d8: 0..31
        const float* xp = x + ((size_t)(b * cS + i0 + i)) * cD + dt0 + d8 * 8;
        float4 f0 = *(const float4*)xp;
        float4 f1 = *(const float4*)(xp + 4);
        float vv[8] = {f0.x, f0.y, f0.z, f0.w, f1.x, f1.y, f1.z, f1.w};
#pragma unroll
        for (int e = 0; e < 8; ++e) {
          union { float f; unsigned u; } cv; cv.f = vv[e];
          xsT[pb][(d8 * 8 + e) * RS + i] = (unsigned short)(cv.u >> 16);
        }
      }
    }
  };

  stage(0, 0);
  __syncthreads();

  int pb = 0;
  for (int i0 = 0; i0 < iend; i0 += KI) {
    if (i0 + KI < iend) stage(pb ^ 1, i0 + KI);

    // ---- A fragments (w values), kc = 0,1 --------------------------------
    short8 af0, af1;
#pragma unroll
    for (int kc = 0; kc < 2; ++kc) {
      short8 af;
#pragma unroll
      for (int e = 0; e < 8; ++e) {
        const int ig = i0 + kc * 16 + half * 8 + e;
        const float d = fmaf((float)ig, invj, -muv);
        float w = __builtin_amdgcn_exp2f(ce * d * d);
        w = (ig <= jrow) ? w : 0.f;
        if (dh == 0) nrm2 += w * w;   // dh=1 waves' snrm is never read
        union { float f; unsigned u; } cv; cv.f = w;
        af[e] = (short)(cv.u >> 16);
      }
      if (kc == 0) af0 = af; else af1 = af;
    }

    // ---- B fragments (one ds_read_b128 each) + MFMA ----------------------
    const int rbase = dh * 128 + n32;
    short8 b00 = *(const short8*)&xsT[pb][(rbase)      * RS + half * 8];
    short8 b01 = *(const short8*)&xsT[pb][(rbase)      * RS + 16 + half * 8];
    short8 b10 = *(const short8*)&xsT[pb][(rbase + 32) * RS + half * 8];
    short8 b11 = *(const short8*)&xsT[pb][(rbase + 32) * RS + 16 + half * 8];
    short8 b20 = *(const short8*)&xsT[pb][(rbase + 64) * RS + half * 8];
    short8 b21 = *(const short8*)&xsT[pb][(rbase + 64) * RS + 16 + half * 8];
    short8 b30 = *(const short8*)&xsT[pb][(rbase + 96) * RS + half * 8];
    short8 b31 = *(const short8*)&xsT[pb][(rbase + 96) * RS + 16 + half * 8];
    acc0 = __builtin_amdgcn_mfma_f32_32x32x16_bf16(af0, b00, acc0, 0, 0, 0);
    acc0 = __builtin_amdgcn_mfma_f32_32x32x16_bf16(af1, b01, acc0, 0, 0, 0);
    acc1 = __builtin_amdgcn_mfma_f32_32x32x16_bf16(af0, b10, acc1, 0, 0, 0);
    acc1 = __builtin_amdgcn_mfma_f32_32x32x16_bf16(af1, b11, acc1, 0, 0, 0);
    acc2 = __builtin_amdgcn_mfma_f32_32x32x16_bf16(af0, b20, acc2, 0, 0, 0);
    acc2 = __builtin_amdgcn_mfma_f32_32x32x16_bf16(af1, b21, acc2, 0, 0, 0);
    acc3 = __builtin_amdgcn_mfma_f32_32x32x16_bf16(af0, b30, acc3, 0, 0, 0);
    acc3 = __builtin_amdgcn_mfma_f32_32x32x16_bf16(af1, b31, acc3, 0, 0, 0);

    __syncthreads();
    pb ^= 1;
  }

  // ---- norms (dh==0 waves are 0,1) ----------------------------------------
  nrm2 += __shfl_xor(nrm2, 32);
  if (wave < 2 && half == 0) snrm[jh][n32] = nrm2;
  __syncthreads();
  if (tid < 64)
    sscl[tid >> 5][tid & 31] =
        __builtin_amdgcn_rcpf(fmaxf(sqrtf(snrm[tid >> 5][tid & 31]), 1e-12f));
  __syncthreads();

  float srow[16];
#pragma unroll
  for (int reg = 0; reg < 16; ++reg) {
    const int row = (reg & 3) + 8 * (reg >> 2) + 4 * half;
    srow[reg] = sscl[jh][row];
  }
#pragma unroll
  for (int reg = 0; reg < 16; ++reg) {
    const int row = (reg & 3) + 8 * (reg >> 2) + 4 * half;
    const int jg = jt0 + jh * 32 + row;
    const int d0 = dt0 + dh * 128 + n32;
    float* op = out + ((size_t)(b * cS + jg)) * cD + d0;
    op[0]  = acc0[reg] * srow[reg];
    op[32] = acc1[reg] * srow[reg];
    op[64] = acc2[reg] * srow[reg];
    op[96] = acc3[reg] * srow[reg];
  }
}

// ---------------------------------------------------------------------------
extern "C" void kernel_launch(void* const* d_in, const int* in_sizes, int n_in,
                              void* d_out, int out_size, void* d_ws, size_t ws_size,
                              hipStream_t stream) {
  const float* x     = (const float*)d_in[0];
  const float* W_ih  = (const float*)d_in[1];
  const float* W_hh  = (const float*)d_in[2];
  const float* b_ih  = (const float*)d_in[3];
  const float* b_hh  = (const float*)d_in[4];
  const float* W_mu  = (const float*)d_in[5];
  const float* b_mu  = (const float*)d_in[6];
  const float* W_sig = (const float*)d_in[7];
  const float* b_sig = (const float*)d_in[8];
  float* out = (float*)d_out;

  char* ws = (char*)d_ws;
  const size_t off_xg  = 0;                                   // 16*80*1024*4
  const size_t off_sig = off_xg  + (size_t)cB*cS*cG*4;
  const size_t off_mu  = off_sig + (size_t)cB*cS*4;
  const size_t off_xbf = off_mu  + (size_t)cB*cS*4;
  const size_t need_bf = off_xbf + (size_t)cB*cS*cD*2;

  float* xgT   = (float*)(ws + off_xg);
  float* sigma = (float*)(ws + off_sig);
  float* mu    = (float*)(ws + off_mu);
  unsigned short* xbf_t = (unsigned short*)(ws + off_xbf);
  const int use_bf = (ws_size >= need_bf) ? 1 : 0;

  k1_xg  <<<dim3(cB * cS / 64), dim3(256), 0, stream>>>(x, W_ih, b_ih, b_hh, xgT, xbf_t, use_bf);
  k2_lstm<<<dim3(cB),           dim3(64),  0, stream>>>(xgT, W_hh, W_mu, b_mu, W_sig, b_sig, sigma, mu);
  k4_attn<<<dim3(cS/TJ, cD/TD, cB), dim3(256), 0, stream>>>(x, xbf_t, use_bf, mu, sigma, out);
}